// Round 1
// baseline (8664.136 us; speedup 1.0000x reference)
//
#include <hip/hip_runtime.h>
#include <math.h>

// ---------------- model constants (baked; START_POS=0) ----------------
#define DIM   2048
#define NH    16
#define HD    128
#define HID   5632
#define NL    4
#define SEQ   512
#define BSZ   2
#define NTOK  (BSZ*SEQ)          // 1024
#define EPS_F 1e-6f
#define SCALE 0.08838834764831845f   // 1/sqrt(128)

// GEMM tile config: 128x128 block tile, BK=16, 256 threads, 8x8 per thread.
#define BM 128
#define BN 128
#define BK 16
#define LDP (BM + 4)   // padded LDS row (132 floats; 528B = 16B-aligned rows)

// ---------------- reductions ----------------
__device__ __forceinline__ float wave_sum(float v) {
    #pragma unroll
    for (int off = 32; off > 0; off >>= 1) v += __shfl_down(v, off);
    return v;
}
__device__ __forceinline__ float wave_max(float v) {
    #pragma unroll
    for (int off = 32; off > 0; off >>= 1) v = fmaxf(v, __shfl_down(v, off));
    return v;
}

// ---------------- embedding gather ----------------
__global__ __launch_bounds__(256) void embed_k(const int* __restrict__ tokens,
                                               const float* __restrict__ emb,
                                               float* __restrict__ h) {
    int row = blockIdx.x;
    int tok = tokens[row];
    const float4* src = (const float4*)(emb + (size_t)tok * DIM);
    float4* dst = (float4*)(h + (size_t)row * DIM);
    int t = threadIdx.x;
    dst[t]       = src[t];
    dst[t + 256] = src[t + 256];
}

// ---------------- RMSNorm (row = 2048) ----------------
__global__ __launch_bounds__(256) void rmsnorm_k(const float* __restrict__ x,
                                                 const float* __restrict__ w,
                                                 float* __restrict__ out) {
    __shared__ float red[4];
    int row = blockIdx.x;
    int t = threadIdx.x;
    const float4* xp = (const float4*)(x + (size_t)row * DIM);
    const float4* wp = (const float4*)w;
    float4 v0 = xp[t], v1 = xp[t + 256];
    float ss = v0.x*v0.x + v0.y*v0.y + v0.z*v0.z + v0.w*v0.w
             + v1.x*v1.x + v1.y*v1.y + v1.z*v1.z + v1.w*v1.w;
    ss = wave_sum(ss);
    if ((t & 63) == 0) red[t >> 6] = ss;
    __syncthreads();
    ss = red[0] + red[1] + red[2] + red[3];
    float r = rsqrtf(ss * (1.0f / DIM) + EPS_F);
    float4 w0 = wp[t], w1v = wp[t + 256];
    float4 o0, o1;
    o0.x = v0.x*r*w0.x; o0.y = v0.y*r*w0.y; o0.z = v0.z*r*w0.z; o0.w = v0.w*r*w0.w;
    o1.x = v1.x*r*w1v.x; o1.y = v1.y*r*w1v.y; o1.z = v1.z*r*w1v.z; o1.w = v1.w*r*w1v.w;
    float4* op = (float4*)(out + (size_t)row * DIM);
    op[t] = o0; op[t + 256] = o1;
}

// ---------------- GEMM C[M,N] = A[M,K] @ B[N,K]^T (+Res), fp32 ----------------
// grid: (N/BN, M/BM, z) ; z selects among up to 3 (B,C) pairs (fused QKV / W1W3).
__global__ __launch_bounds__(256) void gemm_nt(const float* __restrict__ A,
                                               const float* __restrict__ B0,
                                               const float* __restrict__ B1,
                                               const float* __restrict__ B2,
                                               float* __restrict__ C0,
                                               float* __restrict__ C1,
                                               float* __restrict__ C2,
                                               const float* __restrict__ Res,
                                               int K, int lda, int ldb, int ldc) {
    const float* B = (blockIdx.z == 0) ? B0 : (blockIdx.z == 1 ? B1 : B2);
    float* C       = (blockIdx.z == 0) ? C0 : (blockIdx.z == 1 ? C1 : C2);

    __shared__ float As[BK][LDP];   // transposed: As[k][m]
    __shared__ float Bs[BK][LDP];   // transposed: Bs[k][n]

    int t = threadIdx.x;
    int w = t >> 6, l = t & 63;
    int tx8 = l & 7, ty8 = l >> 3;
    int row0 = (w >> 1) * 64 + ty8 * 8;   // tile-local output rows
    int col0 = (w & 1) * 64 + tx8 * 8;    // tile-local output cols
    size_t bm = (size_t)blockIdx.y * BM;
    size_t bn = (size_t)blockIdx.x * BN;

    int lr = t >> 1;          // 0..127 staging row
    int lc = (t & 1) * 8;     // 0 or 8 staging k-offset
    const float* Ag = A + (bm + lr) * (size_t)lda + lc;
    const float* Bg = B + (bn + lr) * (size_t)ldb + lc;

    float acc[8][8] = {};

    for (int k0 = 0; k0 < K; k0 += BK) {
        float4 a0 = *(const float4*)(Ag + k0);
        float4 a1 = *(const float4*)(Ag + k0 + 4);
        float4 b0 = *(const float4*)(Bg + k0);
        float4 b1 = *(const float4*)(Bg + k0 + 4);
        __syncthreads();
        As[lc+0][lr] = a0.x; As[lc+1][lr] = a0.y; As[lc+2][lr] = a0.z; As[lc+3][lr] = a0.w;
        As[lc+4][lr] = a1.x; As[lc+5][lr] = a1.y; As[lc+6][lr] = a1.z; As[lc+7][lr] = a1.w;
        Bs[lc+0][lr] = b0.x; Bs[lc+1][lr] = b0.y; Bs[lc+2][lr] = b0.z; Bs[lc+3][lr] = b0.w;
        Bs[lc+4][lr] = b1.x; Bs[lc+5][lr] = b1.y; Bs[lc+6][lr] = b1.z; Bs[lc+7][lr] = b1.w;
        __syncthreads();
        #pragma unroll
        for (int kk = 0; kk < BK; ++kk) {
            float4 av0 = *(const float4*)&As[kk][row0];
            float4 av1 = *(const float4*)&As[kk][row0 + 4];
            float4 bv0 = *(const float4*)&Bs[kk][col0];
            float4 bv1 = *(const float4*)&Bs[kk][col0 + 4];
            float a[8] = {av0.x, av0.y, av0.z, av0.w, av1.x, av1.y, av1.z, av1.w};
            float b[8] = {bv0.x, bv0.y, bv0.z, bv0.w, bv1.x, bv1.y, bv1.z, bv1.w};
            #pragma unroll
            for (int i = 0; i < 8; ++i)
                #pragma unroll
                for (int j = 0; j < 8; ++j)
                    acc[i][j] = fmaf(a[i], b[j], acc[i][j]);
        }
    }

    #pragma unroll
    for (int i = 0; i < 8; ++i) {
        size_t r = bm + row0 + i;
        float* cp = C + r * (size_t)ldc + bn + col0;
        float4 o0 = make_float4(acc[i][0], acc[i][1], acc[i][2], acc[i][3]);
        float4 o1 = make_float4(acc[i][4], acc[i][5], acc[i][6], acc[i][7]);
        if (Res) {
            const float* rp = Res + r * (size_t)ldc + bn + col0;
            float4 r0 = *(const float4*)rp, r1 = *(const float4*)(rp + 4);
            o0.x += r0.x; o0.y += r0.y; o0.z += r0.z; o0.w += r0.w;
            o1.x += r1.x; o1.y += r1.y; o1.z += r1.z; o1.w += r1.w;
        }
        *(float4*)cp = o0;
        *(float4*)(cp + 4) = o1;
    }
}

// ---------------- RoPE (interleaved pairs), applied to xq and xk in place ----------------
__global__ __launch_bounds__(256) void rope_k(float* __restrict__ xq, float* __restrict__ xk) {
    int idx = blockIdx.x * 256 + threadIdx.x;      // NTOK*NH*64 = 1,048,576
    int row = idx >> 10;                           // token row (b*512+s)
    int rem = idx & 1023;
    int hh = rem >> 6;
    int p  = rem & 63;
    int s  = row & (SEQ - 1);
    double freq = pow(10000.0, -(double)p / 64.0);
    double ang = (double)s * freq;
    float cs = (float)cos(ang), sn = (float)sin(ang);
    size_t base = (size_t)row * DIM + hh * HD + 2 * p;
    float qr = xq[base], qi = xq[base + 1];
    xq[base]     = qr * cs - qi * sn;
    xq[base + 1] = qr * sn + qi * cs;
    float kr = xk[base], ki = xk[base + 1];
    xk[base]     = kr * cs - ki * sn;
    xk[base + 1] = kr * sn + ki * cs;
}

// ---------------- attention scores: S[bh][q][k] = scale*q.k (+causal mask) ----------------
// grid: (kt=4, qt=4, bh=32); 128x128 tile, K=HD=128.
__global__ __launch_bounds__(256) void attn_scores_k(const float* __restrict__ xq,
                                                     const float* __restrict__ xk,
                                                     float* __restrict__ scores) {
    int kt = blockIdx.x, qt = blockIdx.y, bh = blockIdx.z;
    int b = bh >> 4, hh = bh & 15;
    float* S = scores + (size_t)bh * SEQ * SEQ;
    int t = threadIdx.x;

    if (kt > qt) {  // fully masked tile
        float4 ninf = make_float4(-INFINITY, -INFINITY, -INFINITY, -INFINITY);
        for (int i = t; i < 128 * 32; i += 256) {
            int rr = i >> 5, c4 = i & 31;
            ((float4*)(S + (size_t)(qt * 128 + rr) * SEQ + kt * 128))[c4] = ninf;
        }
        return;
    }

    __shared__ float As[BK][LDP];
    __shared__ float Bs[BK][LDP];
    int w = t >> 6, l = t & 63;
    int tx8 = l & 7, ty8 = l >> 3;
    int row0 = (w >> 1) * 64 + ty8 * 8;
    int col0 = (w & 1) * 64 + tx8 * 8;
    int lr = t >> 1, lc = (t & 1) * 8;

    const float* Ag = xq + ((size_t)b * SEQ + qt * 128 + lr) * DIM + hh * HD + lc;
    const float* Bg = xk + ((size_t)b * SEQ + kt * 128 + lr) * DIM + hh * HD + lc;

    float acc[8][8] = {};
    for (int k0 = 0; k0 < HD; k0 += BK) {
        float4 a0 = *(const float4*)(Ag + k0);
        float4 a1 = *(const float4*)(Ag + k0 + 4);
        float4 b0 = *(const float4*)(Bg + k0);
        float4 b1 = *(const float4*)(Bg + k0 + 4);
        __syncthreads();
        As[lc+0][lr] = a0.x; As[lc+1][lr] = a0.y; As[lc+2][lr] = a0.z; As[lc+3][lr] = a0.w;
        As[lc+4][lr] = a1.x; As[lc+5][lr] = a1.y; As[lc+6][lr] = a1.z; As[lc+7][lr] = a1.w;
        Bs[lc+0][lr] = b0.x; Bs[lc+1][lr] = b0.y; Bs[lc+2][lr] = b0.z; Bs[lc+3][lr] = b0.w;
        Bs[lc+4][lr] = b1.x; Bs[lc+5][lr] = b1.y; Bs[lc+6][lr] = b1.z; Bs[lc+7][lr] = b1.w;
        __syncthreads();
        #pragma unroll
        for (int kk = 0; kk < BK; ++kk) {
            float4 av0 = *(const float4*)&As[kk][row0];
            float4 av1 = *(const float4*)&As[kk][row0 + 4];
            float4 bv0 = *(const float4*)&Bs[kk][col0];
            float4 bv1 = *(const float4*)&Bs[kk][col0 + 4];
            float a[8] = {av0.x, av0.y, av0.z, av0.w, av1.x, av1.y, av1.z, av1.w};
            float bb[8] = {bv0.x, bv0.y, bv0.z, bv0.w, bv1.x, bv1.y, bv1.z, bv1.w};
            #pragma unroll
            for (int i = 0; i < 8; ++i)
                #pragma unroll
                for (int j = 0; j < 8; ++j)
                    acc[i][j] = fmaf(a[i], bb[j], acc[i][j]);
        }
    }
    #pragma unroll
    for (int i = 0; i < 8; ++i) {
        int q = qt * 128 + row0 + i;
        float* sp = S + (size_t)q * SEQ + kt * 128 + col0;
        float o[8];
        #pragma unroll
        for (int j = 0; j < 8; ++j) {
            int k = kt * 128 + col0 + j;
            o[j] = (k > q) ? -INFINITY : acc[i][j] * SCALE;
        }
        *(float4*)sp       = make_float4(o[0], o[1], o[2], o[3]);
        *(float4*)(sp + 4) = make_float4(o[4], o[5], o[6], o[7]);
    }
}

// ---------------- row softmax over 512 ----------------
__global__ __launch_bounds__(256) void softmax_k(float* __restrict__ S) {
    __shared__ float redm[4];
    __shared__ float reds[4];
    size_t row = blockIdx.x;
    float* p = S + row * SEQ;
    int t = threadIdx.x;
    float a = p[t], b = p[t + 256];
    float m = wave_max(fmaxf(a, b));
    if ((t & 63) == 0) redm[t >> 6] = m;
    __syncthreads();
    m = fmaxf(fmaxf(redm[0], redm[1]), fmaxf(redm[2], redm[3]));
    float e0 = __expf(a - m), e1 = __expf(b - m);
    float s = wave_sum(e0 + e1);
    if ((t & 63) == 0) reds[t >> 6] = s;
    __syncthreads();
    s = reds[0] + reds[1] + reds[2] + reds[3];
    float inv = 1.0f / s;
    p[t] = e0 * inv;
    p[t + 256] = e1 * inv;
}

// ---------------- P @ V (NN GEMM): O[q][d] = sum_k P[q][k] V[k][d] ----------------
// grid: (qt=4, bh=32); tile 128(sq) x 128(d), K loop to (qt+1)*128 (causal trim).
__global__ __launch_bounds__(256) void attn_pv_k(const float* __restrict__ P,
                                                 const float* __restrict__ xv,
                                                 float* __restrict__ attn) {
    int qt = blockIdx.x, bh = blockIdx.y;
    int b = bh >> 4, hh = bh & 15;
    const float* A = P + (size_t)bh * SEQ * SEQ + (size_t)(qt * 128) * SEQ; // lda=SEQ
    const float* V = xv + (size_t)b * SEQ * DIM + hh * HD;                  // ldb=DIM
    float* C = attn + ((size_t)b * SEQ + qt * 128) * DIM + hh * HD;         // ldc=DIM

    __shared__ float As[BK][LDP];
    __shared__ float Bs[BK][LDP];
    int t = threadIdx.x;
    int w = t >> 6, l = t & 63;
    int tx8 = l & 7, ty8 = l >> 3;
    int row0 = (w >> 1) * 64 + ty8 * 8;
    int col0 = (w & 1) * 64 + tx8 * 8;
    int lr = t >> 1, lc = (t & 1) * 8;       // A staging
    int bkk = t >> 4, bc = (t & 15) * 8;     // B staging

    int Keff = (qt + 1) * 128;
    float acc[8][8] = {};
    for (int k0 = 0; k0 < Keff; k0 += BK) {
        float4 a0 = *(const float4*)(A + (size_t)lr * SEQ + k0 + lc);
        float4 a1 = *(const float4*)(A + (size_t)lr * SEQ + k0 + lc + 4);
        float4 b0 = *(const float4*)(V + (size_t)(k0 + bkk) * DIM + bc);
        float4 b1 = *(const float4*)(V + (size_t)(k0 + bkk) * DIM + bc + 4);
        __syncthreads();
        As[lc+0][lr] = a0.x; As[lc+1][lr] = a0.y; As[lc+2][lr] = a0.z; As[lc+3][lr] = a0.w;
        As[lc+4][lr] = a1.x; As[lc+5][lr] = a1.y; As[lc+6][lr] = a1.z; As[lc+7][lr] = a1.w;
        *(float4*)&Bs[bkk][bc]     = b0;
        *(float4*)&Bs[bkk][bc + 4] = b1;
        __syncthreads();
        #pragma unroll
        for (int kk = 0; kk < BK; ++kk) {
            float4 av0 = *(const float4*)&As[kk][row0];
            float4 av1 = *(const float4*)&As[kk][row0 + 4];
            float4 bv0 = *(const float4*)&Bs[kk][col0];
            float4 bv1 = *(const float4*)&Bs[kk][col0 + 4];
            float a[8] = {av0.x, av0.y, av0.z, av0.w, av1.x, av1.y, av1.z, av1.w};
            float bb[8] = {bv0.x, bv0.y, bv0.z, bv0.w, bv1.x, bv1.y, bv1.z, bv1.w};
            #pragma unroll
            for (int i = 0; i < 8; ++i)
                #pragma unroll
                for (int j = 0; j < 8; ++j)
                    acc[i][j] = fmaf(a[i], bb[j], acc[i][j]);
        }
    }
    #pragma unroll
    for (int i = 0; i < 8; ++i) {
        float* cp = C + (size_t)(row0 + i) * DIM + col0;
        *(float4*)cp       = make_float4(acc[i][0], acc[i][1], acc[i][2], acc[i][3]);
        *(float4*)(cp + 4) = make_float4(acc[i][4], acc[i][5], acc[i][6], acc[i][7]);
    }
}

// ---------------- silu(a)*b ----------------
__global__ __launch_bounds__(256) void silumul_k(const float* __restrict__ a,
                                                 const float* __restrict__ b,
                                                 float* __restrict__ o) {
    size_t i = (size_t)blockIdx.x * 256 + threadIdx.x;  // over float4s
    float4 x = ((const float4*)a)[i];
    float4 y = ((const float4*)b)[i];
    float4 r;
    r.x = x.x / (1.0f + __expf(-x.x)) * y.x;
    r.y = x.y / (1.0f + __expf(-x.y)) * y.y;
    r.z = x.z / (1.0f + __expf(-x.z)) * y.z;
    r.w = x.w / (1.0f + __expf(-x.w)) * y.w;
    ((float4*)o)[i] = r;
}

// ---------------- host ----------------
extern "C" void kernel_launch(void* const* d_in, const int* in_sizes, int n_in,
                              void* d_out, int out_size, void* d_ws, size_t ws_size,
                              hipStream_t stream) {
    (void)in_sizes; (void)n_in; (void)out_size; (void)ws_size;
    const int*   tokens  = (const int*)d_in[0];
    // d_in[1] = start_pos (always 0 in this config)
    const float* tok_emb = (const float*)d_in[2];
    const float* wq  = (const float*)d_in[3];
    const float* wk  = (const float*)d_in[4];
    const float* wv  = (const float*)d_in[5];
    const float* wo  = (const float*)d_in[6];
    const float* w1  = (const float*)d_in[7];
    const float* w2  = (const float*)d_in[8];
    const float* w3  = (const float*)d_in[9];
    const float* anw = (const float*)d_in[10];
    const float* fnw = (const float*)d_in[11];

    float* h  = (float*)d_out;           // hidden state lives in d_out
    float* ws = (float*)d_ws;            // ~122 MB scratch layout:
    float* xn   = ws;                                    // 1024*2048
    float* xq   = xn   + (size_t)NTOK * DIM;             // 1024*2048
    float* xk   = xq   + (size_t)NTOK * DIM;
    float* xv   = xk   + (size_t)NTOK * DIM;
    float* attn = xv   + (size_t)NTOK * DIM;
    float* sc   = attn + (size_t)NTOK * DIM;             // 32*512*512
    float* h1   = sc   + (size_t)BSZ * NH * SEQ * SEQ;   // 1024*5632
    float* h3   = h1   + (size_t)NTOK * HID;

    embed_k<<<NTOK, 256, 0, stream>>>(tokens, tok_emb, h);

    for (int l = 0; l < NL; ++l) {
        const float* lwq = wq + (size_t)l * DIM * DIM;
        const float* lwk = wk + (size_t)l * DIM * DIM;
        const float* lwv = wv + (size_t)l * DIM * DIM;
        const float* lwo = wo + (size_t)l * DIM * DIM;
        const float* lw1 = w1 + (size_t)l * HID * DIM;
        const float* lw2 = w2 + (size_t)l * DIM * HID;
        const float* lw3 = w3 + (size_t)l * HID * DIM;
        const float* lan = anw + (size_t)l * DIM;
        const float* lfn = fnw + (size_t)l * DIM;

        // attention block
        rmsnorm_k<<<NTOK, 256, 0, stream>>>(h, lan, xn);
        gemm_nt<<<dim3(DIM / BN, NTOK / BM, 3), 256, 0, stream>>>(
            xn, lwq, lwk, lwv, xq, xk, xv, nullptr, DIM, DIM, DIM, DIM);
        rope_k<<<(NTOK * NH * 64) / 256, 256, 0, stream>>>(xq, xk);
        attn_scores_k<<<dim3(4, 4, BSZ * NH), 256, 0, stream>>>(xq, xk, sc);
        softmax_k<<<BSZ * NH * SEQ, 256, 0, stream>>>(sc);
        attn_pv_k<<<dim3(4, BSZ * NH), 256, 0, stream>>>(sc, xv, attn);
        gemm_nt<<<dim3(DIM / BN, NTOK / BM, 1), 256, 0, stream>>>(
            attn, lwo, nullptr, nullptr, h, nullptr, nullptr, h, DIM, DIM, DIM, DIM);

        // FFN block
        rmsnorm_k<<<NTOK, 256, 0, stream>>>(h, lfn, xn);
        gemm_nt<<<dim3(HID / BN, NTOK / BM, 2), 256, 0, stream>>>(
            xn, lw1, lw3, nullptr, h1, h3, nullptr, nullptr, DIM, DIM, DIM, HID);
        silumul_k<<<(NTOK * HID / 4) / 256, 256, 0, stream>>>(h1, h3, h1);
        gemm_nt<<<dim3(DIM / BN, NTOK / BM, 1), 256, 0, stream>>>(
            h1, lw2, nullptr, nullptr, h, nullptr, nullptr, h, HID, HID, HID, DIM);
    }
}

// Round 2
// 2949.675 us; speedup vs baseline: 2.9373x; 2.9373x over previous
//
#include <hip/hip_runtime.h>
#include <math.h>

// ---------------- model constants (baked; START_POS=0) ----------------
#define DIM   2048
#define NH    16
#define HD    128
#define HID   5632
#define NL    4
#define SEQ   512
#define BSZ   2
#define NTOK  (BSZ*SEQ)          // 1024
#define EPS_F 1e-6f
#define SCALE 0.08838834764831845f   // 1/sqrt(128)

typedef __bf16 bf16;
typedef __attribute__((ext_vector_type(8))) __bf16 bf16x8;
typedef __attribute__((ext_vector_type(4))) __bf16 bf16x4;
typedef __attribute__((ext_vector_type(4))) float  f32x4;

// fp32 attention tile config (unchanged from R1)
#define BKA 16
#define LDP (128 + 4)

// ---------------- reductions ----------------
__device__ __forceinline__ float wave_sum(float v) {
    #pragma unroll
    for (int off = 32; off > 0; off >>= 1) v += __shfl_down(v, off);
    return v;
}
__device__ __forceinline__ float wave_max(float v) {
    #pragma unroll
    for (int off = 32; off > 0; off >>= 1) v = fmaxf(v, __shfl_down(v, off));
    return v;
}

// ---------------- embedding gather ----------------
__global__ __launch_bounds__(256) void embed_k(const int* __restrict__ tokens,
                                               const float* __restrict__ emb,
                                               float* __restrict__ h) {
    int row = blockIdx.x;
    int tok = tokens[row];
    const float4* src = (const float4*)(emb + (size_t)tok * DIM);
    float4* dst = (float4*)(h + (size_t)row * DIM);
    int t = threadIdx.x;
    dst[t]       = src[t];
    dst[t + 256] = src[t + 256];
}

// ---------------- RMSNorm (row = 2048) ----------------
__global__ __launch_bounds__(256) void rmsnorm_k(const float* __restrict__ x,
                                                 const float* __restrict__ w,
                                                 float* __restrict__ out) {
    __shared__ float red[4];
    int row = blockIdx.x;
    int t = threadIdx.x;
    const float4* xp = (const float4*)(x + (size_t)row * DIM);
    const float4* wp = (const float4*)w;
    float4 v0 = xp[t], v1 = xp[t + 256];
    float ss = v0.x*v0.x + v0.y*v0.y + v0.z*v0.z + v0.w*v0.w
             + v1.x*v1.x + v1.y*v1.y + v1.z*v1.z + v1.w*v1.w;
    ss = wave_sum(ss);
    if ((t & 63) == 0) red[t >> 6] = ss;
    __syncthreads();
    ss = red[0] + red[1] + red[2] + red[3];
    float r = rsqrtf(ss * (1.0f / DIM) + EPS_F);
    float4 w0 = wp[t], w1v = wp[t + 256];
    float4 o0, o1;
    o0.x = v0.x*r*w0.x; o0.y = v0.y*r*w0.y; o0.z = v0.z*r*w0.z; o0.w = v0.w*r*w0.w;
    o1.x = v1.x*r*w1v.x; o1.y = v1.y*r*w1v.y; o1.z = v1.z*r*w1v.z; o1.w = v1.w*r*w1v.w;
    float4* op = (float4*)(out + (size_t)row * DIM);
    op[t] = o0; op[t + 256] = o1;
}

// ---------------- split fp32 -> bf16 hi + bf16 lo ----------------
__global__ __launch_bounds__(256) void split_k(const float* __restrict__ x,
                                               bf16* __restrict__ hi,
                                               bf16* __restrict__ lo) {
    size_t i = ((size_t)blockIdx.x * 256 + threadIdx.x) * 4;
    float4 v = *(const float4*)(x + i);
    bf16 h0 = (bf16)v.x, h1 = (bf16)v.y, h2 = (bf16)v.z, h3 = (bf16)v.w;
    bf16x4 hv; hv[0]=h0; hv[1]=h1; hv[2]=h2; hv[3]=h3;
    bf16x4 lv;
    lv[0] = (bf16)(v.x - (float)h0);
    lv[1] = (bf16)(v.y - (float)h1);
    lv[2] = (bf16)(v.z - (float)h2);
    lv[3] = (bf16)(v.w - (float)h3);
    *(bf16x4*)(hi + i) = hv;
    *(bf16x4*)(lo + i) = lv;
}

// ---------------- zero fill (float4 granular) ----------------
__global__ __launch_bounds__(256) void zero_k(float4* __restrict__ p) {
    size_t i = (size_t)blockIdx.x * 256 + threadIdx.x;
    p[i] = make_float4(0.f, 0.f, 0.f, 0.f);
}

// ---------------- MFMA GEMM: C[M,N] (+)= A[M,K] @ B[N,K]^T ----------------
// A pre-split to bf16 hi/lo; B fp32, split in-kernel during staging.
// 3-product split-bf16: hi*hi + hi*lo + lo*hi (fp32 acc) ~ fp32 precision.
// 128x128 tile, BK=32, 256 threads = 4 waves (each 64x64 = 4x4 mfma tiles).
// grid.z = nmat * kchunks; kchunks>1 -> atomicAdd epilogue (C pre-initialized).
__global__ __launch_bounds__(256, 2) void gemm_bf16x3(
    const bf16* __restrict__ Ahg, const bf16* __restrict__ Alg,
    const float* __restrict__ B0, const float* __restrict__ B1, const float* __restrict__ B2,
    float* __restrict__ C0, float* __restrict__ C1, float* __restrict__ C2,
    int K, int kchunks, int ldc, int doAtomic)
{
    int mat = blockIdx.z / kchunks;
    int kc  = blockIdx.z % kchunks;
    const float* B = (mat == 0) ? B0 : (mat == 1 ? B1 : B2);
    float* C       = (mat == 0) ? C0 : (mat == 1 ? C1 : C2);

    __shared__ bf16 Ah[128][32];
    __shared__ bf16 Al[128][32];
    __shared__ bf16 Bh[128][32];
    __shared__ bf16 Bl[128][32];

    int t = threadIdx.x;
    int l = t & 63, w = t >> 6;
    int ml = l & 15, q8 = (l >> 4) * 8;
    int wm = (w >> 1) * 64, wn = (w & 1) * 64;
    size_t bm = (size_t)blockIdx.y * 128;
    size_t bn = (size_t)blockIdx.x * 128;

    // A staging: thread covers chunks t and t+256: row = c>>2 (0..127), ch = c&3
    int ar = t >> 2, ac = (t & 3) * 8;
    // B staging: thread covers 16 consecutive k of one row
    int br = t >> 1, bc = (t & 1) * 16;

    int kpc = K / kchunks;
    int kbeg = kc * kpc, kend = kbeg + kpc;

    const bf16* Ahp0 = Ahg + (bm + ar) * (size_t)K + ac;
    const bf16* Alp0 = Alg + (bm + ar) * (size_t)K + ac;
    const bf16* Ahp1 = Ahg + (bm + ar + 64) * (size_t)K + ac;
    const bf16* Alp1 = Alg + (bm + ar + 64) * (size_t)K + ac;
    const float* Bp  = B + (bn + br) * (size_t)K + bc;

    f32x4 acc[4][4] = {};

    for (int k0 = kbeg; k0 < kend; k0 += 32) {
        // global loads (A already bf16 hi/lo; B fp32)
        float4 ah0 = *(const float4*)(Ahp0 + k0);
        float4 ah1 = *(const float4*)(Ahp1 + k0);
        float4 al0 = *(const float4*)(Alp0 + k0);
        float4 al1 = *(const float4*)(Alp1 + k0);
        float4 w0 = *(const float4*)(Bp + k0);
        float4 w1 = *(const float4*)(Bp + k0 + 4);
        float4 w2 = *(const float4*)(Bp + k0 + 8);
        float4 w3 = *(const float4*)(Bp + k0 + 12);

        __syncthreads();   // previous stage's LDS reads done

        *(float4*)&Ah[ar][ac]      = ah0;
        *(float4*)&Ah[ar + 64][ac] = ah1;
        *(float4*)&Al[ar][ac]      = al0;
        *(float4*)&Al[ar + 64][ac] = al1;

        float wf[16] = {w0.x, w0.y, w0.z, w0.w, w1.x, w1.y, w1.z, w1.w,
                        w2.x, w2.y, w2.z, w2.w, w3.x, w3.y, w3.z, w3.w};
        bf16x8 vh0, vh1, vl0, vl1;
        #pragma unroll
        for (int i = 0; i < 8; ++i) {
            bf16 h = (bf16)wf[i];
            vh0[i] = h; vl0[i] = (bf16)(wf[i] - (float)h);
        }
        #pragma unroll
        for (int i = 0; i < 8; ++i) {
            bf16 h = (bf16)wf[8 + i];
            vh1[i] = h; vl1[i] = (bf16)(wf[8 + i] - (float)h);
        }
        *(bf16x8*)&Bh[br][bc]     = vh0;
        *(bf16x8*)&Bh[br][bc + 8] = vh1;
        *(bf16x8*)&Bl[br][bc]     = vl0;
        *(bf16x8*)&Bl[br][bc + 8] = vl1;

        __syncthreads();

        bf16x8 afh[4], afl[4], bfh[4], bfl[4];
        #pragma unroll
        for (int i = 0; i < 4; ++i) {
            afh[i] = *(const bf16x8*)&Ah[wm + i * 16 + ml][q8];
            afl[i] = *(const bf16x8*)&Al[wm + i * 16 + ml][q8];
            bfh[i] = *(const bf16x8*)&Bh[wn + i * 16 + ml][q8];
            bfl[i] = *(const bf16x8*)&Bl[wn + i * 16 + ml][q8];
        }
        #pragma unroll
        for (int i = 0; i < 4; ++i)
            #pragma unroll
            for (int j = 0; j < 4; ++j) {
                acc[i][j] = __builtin_amdgcn_mfma_f32_16x16x32_bf16(afh[i], bfl[j], acc[i][j], 0, 0, 0);
                acc[i][j] = __builtin_amdgcn_mfma_f32_16x16x32_bf16(afl[i], bfh[j], acc[i][j], 0, 0, 0);
                acc[i][j] = __builtin_amdgcn_mfma_f32_16x16x32_bf16(afh[i], bfh[j], acc[i][j], 0, 0, 0);
            }
    }

    // epilogue: C/D layout col=lane&15, row=(lane>>4)*4+reg
    int r0 = (l >> 4) * 4;
    int cl = l & 15;
    if (doAtomic) {
        #pragma unroll
        for (int i = 0; i < 4; ++i)
            #pragma unroll
            for (int j = 0; j < 4; ++j) {
                size_t base = (bm + wm + i * 16 + r0) * (size_t)ldc + bn + wn + j * 16 + cl;
                #pragma unroll
                for (int r = 0; r < 4; ++r)
                    atomicAdd(&C[base + (size_t)r * ldc], acc[i][j][r]);
            }
    } else {
        #pragma unroll
        for (int i = 0; i < 4; ++i)
            #pragma unroll
            for (int j = 0; j < 4; ++j) {
                size_t base = (bm + wm + i * 16 + r0) * (size_t)ldc + bn + wn + j * 16 + cl;
                #pragma unroll
                for (int r = 0; r < 4; ++r)
                    C[base + (size_t)r * ldc] = acc[i][j][r];
            }
    }
}

// ---------------- RoPE table (one-time) ----------------
__global__ __launch_bounds__(256) void rope_tab_k(float* __restrict__ tab) {
    int idx = blockIdx.x * 256 + threadIdx.x;   // 512*64
    int s = idx >> 6, p = idx & 63;
    double freq = pow(10000.0, -(double)p / 64.0);
    double ang = (double)s * freq;
    tab[idx * 2]     = (float)cos(ang);
    tab[idx * 2 + 1] = (float)sin(ang);
}

// ---------------- RoPE apply (interleaved pairs) ----------------
__global__ __launch_bounds__(256) void rope_k(float* __restrict__ xq,
                                              float* __restrict__ xk,
                                              const float* __restrict__ tab) {
    int idx = blockIdx.x * 256 + threadIdx.x;      // NTOK*NH*64
    int row = idx >> 10;
    int rem = idx & 1023;
    int hh = rem >> 6;
    int p  = rem & 63;
    int s  = row & (SEQ - 1);
    float cs = tab[(s * 64 + p) * 2];
    float sn = tab[(s * 64 + p) * 2 + 1];
    size_t base = (size_t)row * DIM + hh * HD + 2 * p;
    float qr = xq[base], qi = xq[base + 1];
    xq[base]     = qr * cs - qi * sn;
    xq[base + 1] = qr * sn + qi * cs;
    float kr = xk[base], ki = xk[base + 1];
    xk[base]     = kr * cs - ki * sn;
    xk[base + 1] = kr * sn + ki * cs;
}

// ---------------- attention scores (fp32 vector tile GEMM) ----------------
__global__ __launch_bounds__(256) void attn_scores_k(const float* __restrict__ xq,
                                                     const float* __restrict__ xk,
                                                     float* __restrict__ scores) {
    int kt = blockIdx.x, qt = blockIdx.y, bh = blockIdx.z;
    int b = bh >> 4, hh = bh & 15;
    float* S = scores + (size_t)bh * SEQ * SEQ;
    int t = threadIdx.x;

    if (kt > qt) {  // fully masked tile
        float4 ninf = make_float4(-INFINITY, -INFINITY, -INFINITY, -INFINITY);
        for (int i = t; i < 128 * 32; i += 256) {
            int rr = i >> 5, c4 = i & 31;
            ((float4*)(S + (size_t)(qt * 128 + rr) * SEQ + kt * 128))[c4] = ninf;
        }
        return;
    }

    __shared__ float As[BKA][LDP];
    __shared__ float Bs[BKA][LDP];
    int w = t >> 6, l = t & 63;
    int tx8 = l & 7, ty8 = l >> 3;
    int row0 = (w >> 1) * 64 + ty8 * 8;
    int col0 = (w & 1) * 64 + tx8 * 8;
    int lr = t >> 1, lc = (t & 1) * 8;

    const float* Ag = xq + ((size_t)b * SEQ + qt * 128 + lr) * DIM + hh * HD + lc;
    const float* Bg = xk + ((size_t)b * SEQ + kt * 128 + lr) * DIM + hh * HD + lc;

    float acc[8][8] = {};
    for (int k0 = 0; k0 < HD; k0 += BKA) {
        float4 a0 = *(const float4*)(Ag + k0);
        float4 a1 = *(const float4*)(Ag + k0 + 4);
        float4 b0 = *(const float4*)(Bg + k0);
        float4 b1 = *(const float4*)(Bg + k0 + 4);
        __syncthreads();
        As[lc+0][lr] = a0.x; As[lc+1][lr] = a0.y; As[lc+2][lr] = a0.z; As[lc+3][lr] = a0.w;
        As[lc+4][lr] = a1.x; As[lc+5][lr] = a1.y; As[lc+6][lr] = a1.z; As[lc+7][lr] = a1.w;
        Bs[lc+0][lr] = b0.x; Bs[lc+1][lr] = b0.y; Bs[lc+2][lr] = b0.z; Bs[lc+3][lr] = b0.w;
        Bs[lc+4][lr] = b1.x; Bs[lc+5][lr] = b1.y; Bs[lc+6][lr] = b1.z; Bs[lc+7][lr] = b1.w;
        __syncthreads();
        #pragma unroll
        for (int kk = 0; kk < BKA; ++kk) {
            float4 av0 = *(const float4*)&As[kk][row0];
            float4 av1 = *(const float4*)&As[kk][row0 + 4];
            float4 bv0 = *(const float4*)&Bs[kk][col0];
            float4 bv1 = *(const float4*)&Bs[kk][col0 + 4];
            float a[8] = {av0.x, av0.y, av0.z, av0.w, av1.x, av1.y, av1.z, av1.w};
            float bb[8] = {bv0.x, bv0.y, bv0.z, bv0.w, bv1.x, bv1.y, bv1.z, bv1.w};
            #pragma unroll
            for (int i = 0; i < 8; ++i)
                #pragma unroll
                for (int j = 0; j < 8; ++j)
                    acc[i][j] = fmaf(a[i], bb[j], acc[i][j]);
        }
    }
    #pragma unroll
    for (int i = 0; i < 8; ++i) {
        int q = qt * 128 + row0 + i;
        float* sp = S + (size_t)q * SEQ + kt * 128 + col0;
        float o[8];
        #pragma unroll
        for (int j = 0; j < 8; ++j) {
            int k = kt * 128 + col0 + j;
            o[j] = (k > q) ? -INFINITY : acc[i][j] * SCALE;
        }
        *(float4*)sp       = make_float4(o[0], o[1], o[2], o[3]);
        *(float4*)(sp + 4) = make_float4(o[4], o[5], o[6], o[7]);
    }
}

// ---------------- row softmax over 512 ----------------
__global__ __launch_bounds__(256) void softmax_k(float* __restrict__ S) {
    __shared__ float redm[4];
    __shared__ float reds[4];
    size_t row = blockIdx.x;
    float* p = S + row * SEQ;
    int t = threadIdx.x;
    float a = p[t], b = p[t + 256];
    float m = wave_max(fmaxf(a, b));
    if ((t & 63) == 0) redm[t >> 6] = m;
    __syncthreads();
    m = fmaxf(fmaxf(redm[0], redm[1]), fmaxf(redm[2], redm[3]));
    float e0 = __expf(a - m), e1 = __expf(b - m);
    float s = wave_sum(e0 + e1);
    if ((t & 63) == 0) reds[t >> 6] = s;
    __syncthreads();
    s = reds[0] + reds[1] + reds[2] + reds[3];
    float inv = 1.0f / s;
    p[t] = e0 * inv;
    p[t + 256] = e1 * inv;
}

// ---------------- P @ V (fp32 NN tile GEMM) ----------------
__global__ __launch_bounds__(256) void attn_pv_k(const float* __restrict__ P,
                                                 const float* __restrict__ xv,
                                                 float* __restrict__ attn) {
    int qt = blockIdx.x, bh = blockIdx.y;
    int b = bh >> 4, hh = bh & 15;
    const float* A = P + (size_t)bh * SEQ * SEQ + (size_t)(qt * 128) * SEQ;
    const float* V = xv + (size_t)b * SEQ * DIM + hh * HD;
    float* C = attn + ((size_t)b * SEQ + qt * 128) * DIM + hh * HD;

    __shared__ float As[BKA][LDP];
    __shared__ float Bs[BKA][LDP];
    int t = threadIdx.x;
    int w = t >> 6, l = t & 63;
    int tx8 = l & 7, ty8 = l >> 3;
    int row0 = (w >> 1) * 64 + ty8 * 8;
    int col0 = (w & 1) * 64 + tx8 * 8;
    int lr = t >> 1, lc = (t & 1) * 8;
    int bkk = t >> 4, bc = (t & 15) * 8;

    int Keff = (qt + 1) * 128;
    float acc[8][8] = {};
    for (int k0 = 0; k0 < Keff; k0 += BKA) {
        float4 a0 = *(const float4*)(A + (size_t)lr * SEQ + k0 + lc);
        float4 a1 = *(const float4*)(A + (size_t)lr * SEQ + k0 + lc + 4);
        float4 b0 = *(const float4*)(V + (size_t)(k0 + bkk) * DIM + bc);
        float4 b1 = *(const float4*)(V + (size_t)(k0 + bkk) * DIM + bc + 4);
        __syncthreads();
        As[lc+0][lr] = a0.x; As[lc+1][lr] = a0.y; As[lc+2][lr] = a0.z; As[lc+3][lr] = a0.w;
        As[lc+4][lr] = a1.x; As[lc+5][lr] = a1.y; As[lc+6][lr] = a1.z; As[lc+7][lr] = a1.w;
        *(float4*)&Bs[bkk][bc]     = b0;
        *(float4*)&Bs[bkk][bc + 4] = b1;
        __syncthreads();
        #pragma unroll
        for (int kk = 0; kk < BKA; ++kk) {
            float4 av0 = *(const float4*)&As[kk][row0];
            float4 av1 = *(const float4*)&As[kk][row0 + 4];
            float4 bv0 = *(const float4*)&Bs[kk][col0];
            float4 bv1 = *(const float4*)&Bs[kk][col0 + 4];
            float a[8] = {av0.x, av0.y, av0.z, av0.w, av1.x, av1.y, av1.z, av1.w};
            float bb[8] = {bv0.x, bv0.y, bv0.z, bv0.w, bv1.x, bv1.y, bv1.z, bv1.w};
            #pragma unroll
            for (int i = 0; i < 8; ++i)
                #pragma unroll
                for (int j = 0; j < 8; ++j)
                    acc[i][j] = fmaf(a[i], bb[j], acc[i][j]);
        }
    }
    #pragma unroll
    for (int i = 0; i < 8; ++i) {
        float* cp = C + (size_t)(row0 + i) * DIM + col0;
        *(float4*)cp       = make_float4(acc[i][0], acc[i][1], acc[i][2], acc[i][3]);
        *(float4*)(cp + 4) = make_float4(acc[i][4], acc[i][5], acc[i][6], acc[i][7]);
    }
}

// ---------------- silu(a)*b ----------------
__global__ __launch_bounds__(256) void silumul_k(const float* __restrict__ a,
                                                 const float* __restrict__ b,
                                                 float* __restrict__ o) {
    size_t i = (size_t)blockIdx.x * 256 + threadIdx.x;
    float4 x = ((const float4*)a)[i];
    float4 y = ((const float4*)b)[i];
    float4 r;
    r.x = x.x / (1.0f + __expf(-x.x)) * y.x;
    r.y = x.y / (1.0f + __expf(-x.y)) * y.y;
    r.z = x.z / (1.0f + __expf(-x.z)) * y.z;
    r.w = x.w / (1.0f + __expf(-x.w)) * y.w;
    ((float4*)o)[i] = r;
}

// ---------------- host ----------------
extern "C" void kernel_launch(void* const* d_in, const int* in_sizes, int n_in,
                              void* d_out, int out_size, void* d_ws, size_t ws_size,
                              hipStream_t stream) {
    (void)in_sizes; (void)n_in; (void)out_size; (void)ws_size;
    const int*   tokens  = (const int*)d_in[0];
    const float* tok_emb = (const float*)d_in[2];
    const float* wq  = (const float*)d_in[3];
    const float* wk  = (const float*)d_in[4];
    const float* wv  = (const float*)d_in[5];
    const float* wo  = (const float*)d_in[6];
    const float* w1  = (const float*)d_in[7];
    const float* w2  = (const float*)d_in[8];
    const float* w3  = (const float*)d_in[9];
    const float* anw = (const float*)d_in[10];
    const float* fnw = (const float*)d_in[11];

    float* h  = (float*)d_out;
    float* ws = (float*)d_ws;
    float* xn   = ws;                                    // 2.10M f
    float* xq   = xn   + (size_t)NTOK * DIM;             // 2.10M f (xq,xk,xv contiguous)
    float* xk   = xq   + (size_t)NTOK * DIM;
    float* xv   = xk   + (size_t)NTOK * DIM;
    float* attn = xv   + (size_t)NTOK * DIM;
    float* sc   = attn + (size_t)NTOK * DIM;             // 8.39M f (scores OR A-split overlay)
    float* h1   = sc   + (size_t)BSZ * NH * SEQ * SEQ;   // 5.77M f
    float* h3   = h1   + (size_t)NTOK * HID;
    float* tab  = h3   + (size_t)NTOK * HID;             // 64K f rope table
    // A-split overlay in the scores region (temporally disjoint with probs):
    bf16* a_hi = (bf16*)sc;
    bf16* a_lo = a_hi + (size_t)NTOK * HID;              // max M*K = 1024*5632

    rope_tab_k<<<(SEQ * 64) / 256, 256, 0, stream>>>(tab);
    embed_k<<<NTOK, 256, 0, stream>>>(tokens, tok_emb, h);

    for (int l = 0; l < NL; ++l) {
        const float* lwq = wq + (size_t)l * DIM * DIM;
        const float* lwk = wk + (size_t)l * DIM * DIM;
        const float* lwv = wv + (size_t)l * DIM * DIM;
        const float* lwo = wo + (size_t)l * DIM * DIM;
        const float* lw1 = w1 + (size_t)l * HID * DIM;
        const float* lw2 = w2 + (size_t)l * DIM * HID;
        const float* lw3 = w3 + (size_t)l * HID * DIM;
        const float* lan = anw + (size_t)l * DIM;
        const float* lfn = fnw + (size_t)l * DIM;

        // ---- attention block ----
        rmsnorm_k<<<NTOK, 256, 0, stream>>>(h, lan, xn);
        split_k<<<(NTOK * DIM / 4) / 256, 256, 0, stream>>>(xn, a_hi, a_lo);
        zero_k<<<(3 * NTOK * DIM / 4) / 256, 256, 0, stream>>>((float4*)xq);
        gemm_bf16x3<<<dim3(DIM / 128, NTOK / 128, 6), 256, 0, stream>>>(
            a_hi, a_lo, lwq, lwk, lwv, xq, xk, xv, DIM, 2, DIM, 1);
        rope_k<<<(NTOK * NH * 64) / 256, 256, 0, stream>>>(xq, xk, tab);
        attn_scores_k<<<dim3(4, 4, BSZ * NH), 256, 0, stream>>>(xq, xk, sc);
        softmax_k<<<BSZ * NH * SEQ, 256, 0, stream>>>(sc);
        attn_pv_k<<<dim3(4, BSZ * NH), 256, 0, stream>>>(sc, xv, attn);
        split_k<<<(NTOK * DIM / 4) / 256, 256, 0, stream>>>(attn, a_hi, a_lo);
        gemm_bf16x3<<<dim3(DIM / 128, NTOK / 128, 4), 256, 0, stream>>>(
            a_hi, a_lo, lwo, nullptr, nullptr, h, nullptr, nullptr, DIM, 4, DIM, 1);

        // ---- FFN block ----
        rmsnorm_k<<<NTOK, 256, 0, stream>>>(h, lfn, xn);
        split_k<<<(NTOK * DIM / 4) / 256, 256, 0, stream>>>(xn, a_hi, a_lo);
        gemm_bf16x3<<<dim3(HID / 128, NTOK / 128, 2), 256, 0, stream>>>(
            a_hi, a_lo, lw1, lw3, nullptr, h1, h3, nullptr, DIM, 1, HID, 0);
        silumul_k<<<(NTOK * HID / 4) / 256, 256, 0, stream>>>(h1, h3, h1);
        split_k<<<(NTOK * HID / 4) / 256, 256, 0, stream>>>(h1, a_hi, a_lo);
        gemm_bf16x3<<<dim3(DIM / 128, NTOK / 128, 4), 256, 0, stream>>>(
            a_hi, a_lo, lw2, nullptr, nullptr, h, nullptr, nullptr, HID, 4, DIM, 1);
    }
}